// Round 6
// baseline (320.692 us; speedup 1.0000x reference)
//
#include <hip/hip_runtime.h>
#include <stdint.h>

// Problem constants (fixed by setup_inputs)
#define B_SZ 2048          // batch
#define D_SZ 2047          // state dim
#define KD   2048          // D+1 == hash_size
#define K_SZ 4096          // input_length (rows of A)
#define TABLE_MASK ((1u << 22) - 1)
#define MARGIN 0.03f       // 3-pass bf16-split worst-case error ~1.3e-2; 2.3x headroom

// R3 MID-path tile constants
#define TJ 128
#define TK 128
#define BK 32

typedef __attribute__((ext_vector_type(8))) short bf16x8;
typedef __attribute__((ext_vector_type(4))) float f32x4;
typedef unsigned short ushort_t;

__device__ __forceinline__ unsigned short f2bf_rn(float x) {
    unsigned int u = __builtin_bit_cast(unsigned int, x);
    unsigned int lsb = (u >> 16) & 1u;
    u += 0x7fffu + lsb;                 // round-to-nearest-even
    return (unsigned short)(u >> 16);
}
__device__ __forceinline__ float bf2f(unsigned short h) {
    unsigned int u = ((unsigned int)h) << 16;
    return __builtin_bit_cast(float, u);
}
__device__ __forceinline__ void gl_lds16(const void* g, void* l) {
    __builtin_amdgcn_global_load_lds(
        (const __attribute__((address_space(1))) unsigned int*)g,
        (__attribute__((address_space(3))) unsigned int*)l, 16, 0, 0);
}

#define BAR()   asm volatile("s_barrier" ::: "memory")
#define LGKM0() asm volatile("s_waitcnt lgkmcnt(0)" ::: "memory")
#define VM10()  asm volatile("s_waitcnt vmcnt(10)" ::: "memory")
#define VM0()   asm volatile("s_waitcnt vmcnt(0)" ::: "memory")

// ===========================================================================
// 8-PHASE PATH. Planes stored as the exact LDS image:
//   S: [P(8 panels of 256 rows)][dt(32 K-tiles of 64)][prow 256][8 chunks x 8]
//      row permutation: p = bitswap6,7(r); chunk swizzle: stored cs holds
//      logical chunk c = cs ^ (p&7).
//   A: same but p: p7=r5, p6:5=r7:6, p4:0=r4:0 (stage halves on bit5).
// ===========================================================================
__global__ __launch_bounds__(256)
void opiq_split8(const float* __restrict__ states,
                 const float* __restrict__ actions,
                 const float* __restrict__ A,
                 ushort_t* __restrict__ Shi_p, ushort_t* __restrict__ Slo_p,
                 ushort_t* __restrict__ Ahi_p, ushort_t* __restrict__ Alo_p)
{
    const int SCHUNKS = 524288;            // 2048*2048/8
    const int TCHUNKS = 1572864;           // + 4096*2048/8
    const int i = blockIdx.x * 256 + threadIdx.x;
    if (i >= TCHUNKS) return;
    const bool isS = (i < SCHUNKS);
    const int c  = isS ? i : (i - SCHUNKS);
    const int cs = c & 7;
    const int p  = (c >> 3) & 255;
    const int dt = (c >> 11) & 31;
    const int Pn = c >> 16;                // S: [0,8)  A: [0,16)
    const int rloc = isS
        ? ((((p >> 6) & 1) << 7) | (((p >> 7) & 1) << 6) | (p & 63))
        : ((((p >> 5) & 3) << 6) | (((p >> 7) & 1) << 5) | (p & 31));
    const int row   = Pn * 256 + rloc;
    const int dbase = dt * 64 + ((cs ^ (p & 7)) << 3);

    float v[8];
    if (isS) {
#pragma unroll
        for (int e = 0; e < 8; ++e) {
            const int d = dbase + e;
            v[e] = (d == D_SZ) ? actions[row] : states[(size_t)row * D_SZ + d];
        }
    } else {
        const float4 a0 = *reinterpret_cast<const float4*>(&A[(size_t)row * KD + dbase]);
        const float4 a1 = *reinterpret_cast<const float4*>(&A[(size_t)row * KD + dbase + 4]);
        v[0]=a0.x; v[1]=a0.y; v[2]=a0.z; v[3]=a0.w;
        v[4]=a1.x; v[5]=a1.y; v[6]=a1.z; v[7]=a1.w;
    }
    bf16x8 hv, lv;
#pragma unroll
    for (int e = 0; e < 8; ++e) {
        const ushort_t h = f2bf_rn(v[e]);
        hv[e] = (short)h;
        lv[e] = (short)f2bf_rn(v[e] - bf2f(h));
    }
    const size_t off = (((size_t)Pn * 32 + dt) << 14) + p * 64 + cs * 8;
    if (isS) { *(bf16x8*)&Shi_p[off] = hv; *(bf16x8*)&Slo_p[off] = lv; }
    else     { *(bf16x8*)&Ahi_p[off] = hv; *(bf16x8*)&Alo_p[off] = lv; }
}

// 256x256 tile, BK=64, K' = 6144 (3 segs), K-split x2 -> 48 K-tiles/block.
// 4 phases/K-tile, 16 MFMA/phase, counted vmcnt(10), tile-pair semaphore.
__global__ __launch_bounds__(512, 1)
void opiq_gemm_8ph(const ushort_t* __restrict__ Shi_p, const ushort_t* __restrict__ Slo_p,
                   const ushort_t* __restrict__ Ahi_p, const ushort_t* __restrict__ Alo_p,
                   const float* __restrict__ bvec,
                   const int* __restrict__ hash_coeffs,
                   float* __restrict__ Cpart,
                   unsigned int* __restrict__ flag_arrive,
                   unsigned int* __restrict__ flag_ready,
                   unsigned int* __restrict__ hash_acc,
                   unsigned int* __restrict__ defer_cnt,
                   unsigned int* __restrict__ defer_list,
                   unsigned int defer_cap)
{
    __shared__ __align__(16) ushort_t lds[2 * 32768];   // 128 KB: [buf][S 16K | A 16K]
    __shared__ unsigned int role_sh;

    const int tid  = threadIdx.x;
    const int lane = tid & 63;
    const int wid  = tid >> 6;          // 8 waves: 2(M) x 4(N)
    const int wm   = wid >> 2;
    const int wn   = wid & 3;
    const int l15  = lane & 15, lq = lane >> 4;

    // XCD swizzle (256 % 8 == 0, bijective); kh pair mates on same XCD.
    const int bid = blockIdx.x;
    const int swz = (bid & 7) * 32 + (bid >> 3);
    const int tile = swz >> 1;          // [0,128)
    const int kh   = swz & 1;
    const int by   = tile >> 4;         // [0,8)
    const int bx   = tile & 15;         // [0,16)
    const int kt0  = kh * 48;
    const int NT   = 48;

    // permuted-row indices for fragment reads (stored p; swizzle key = p&7)
    int pS[8], pA[4];
#pragma unroll
    for (int m = 0; m < 8; ++m) {
        const int r = wm * 128 + m * 16 + l15;
        pS[m] = (((r >> 6) & 1) << 7) | (((r >> 7) & 1) << 6) | (r & 63);
    }
#pragma unroll
    for (int n = 0; n < 4; ++n) {
        const int r = wn * 64 + n * 16 + l15;
        pA[n] = (((r >> 5) & 1) << 7) | (((r >> 6) & 3) << 5) | (r & 31);
    }

    f32x4 acc[8][4];
#pragma unroll
    for (int m = 0; m < 8; ++m)
#pragma unroll
        for (int n = 0; n < 4; ++n) acc[m][n] = (f32x4){0.f, 0.f, 0.f, 0.f};

    auto readS = [&](int buf, int m, int kk) -> bf16x8 {
        const int idx = buf * 32768 + pS[m] * 64 + ((((kk << 2) | lq) ^ (pS[m] & 7)) << 3);
        return *reinterpret_cast<const bf16x8*>(&lds[idx]);
    };
    auto readA = [&](int buf, int n, int kk) -> bf16x8 {
        const int idx = buf * 32768 + 16384 + pA[n] * 64 + ((((kk << 2) | lq) ^ (pA[n] & 7)) << 3);
        return *reinterpret_cast<const bf16x8*>(&lds[idx]);
    };
    // stage one half (2 x gl_lds16/thread). S plane: seg<2 -> hi; A: seg==1 -> lo.
    auto stage_S = [&](int kt, int h, int buf) {
        const ushort_t* src = ((kt < 64) ? Shi_p : Slo_p)
            + (((size_t)(by * 32 + (kt & 31))) << 14) + (h << 13) + tid * 8;
        const int dst = buf * 32768 + (h << 13) + tid * 8;
        gl_lds16(src, &lds[dst]);
        gl_lds16(src + 4096, &lds[dst + 4096]);
    };
    auto stage_A = [&](int kt, int h, int buf) {
        const ushort_t* src = ((((kt >> 5)) == 1) ? Alo_p : Ahi_p)
            + (((size_t)(bx * 32 + (kt & 31))) << 14) + (h << 13) + tid * 8;
        const int dst = buf * 32768 + 16384 + (h << 13) + tid * 8;
        gl_lds16(src, &lds[dst]);
        gl_lds16(src + 4096, &lds[dst + 4096]);
    };

    // prologue: fully stage tiles 0 and 1, drain once
    stage_S(kt0 + 0, 0, 0); stage_S(kt0 + 0, 1, 0);
    stage_A(kt0 + 0, 0, 0); stage_A(kt0 + 0, 1, 0);
    stage_S(kt0 + 1, 0, 1); stage_S(kt0 + 1, 1, 1);
    stage_A(kt0 + 1, 0, 1); stage_A(kt0 + 1, 1, 1);
    VM0();
    BAR();

    bf16x8 sq[4][2], aq0[2][2], aq1[2][2];

#pragma unroll 1
    for (int t = 0; t < NT - 2; ++t) {
        const int buf = t & 1;
        const int ktn = kt0 + t + 2;
        // ---- ph1: read S q0 + A q0; MFMA q(0,0)
#pragma unroll
        for (int mi = 0; mi < 4; ++mi)
#pragma unroll
            for (int kk = 0; kk < 2; ++kk) sq[mi][kk] = readS(buf, mi, kk);
#pragma unroll
        for (int ni = 0; ni < 2; ++ni)
#pragma unroll
            for (int kk = 0; kk < 2; ++kk) aq0[ni][kk] = readA(buf, ni, kk);
        BAR(); LGKM0();
        __builtin_amdgcn_s_setprio(1);
#pragma unroll
        for (int ni = 0; ni < 2; ++ni)
#pragma unroll
            for (int kk = 0; kk < 2; ++kk)
#pragma unroll
                for (int mi = 0; mi < 4; ++mi)
                    acc[mi][ni] = __builtin_amdgcn_mfma_f32_16x16x32_bf16(sq[mi][kk], aq0[ni][kk], acc[mi][ni], 0, 0, 0);
        __builtin_amdgcn_s_setprio(0);
        BAR();
        // ---- ph2: read A q1; stage S-half0(t+2); MFMA q(0,1)
#pragma unroll
        for (int ni = 0; ni < 2; ++ni)
#pragma unroll
            for (int kk = 0; kk < 2; ++kk) aq1[ni][kk] = readA(buf, 2 + ni, kk);
        stage_S(ktn, 0, buf);
        VM10();
        BAR(); LGKM0();
        __builtin_amdgcn_s_setprio(1);
#pragma unroll
        for (int ni = 0; ni < 2; ++ni)
#pragma unroll
            for (int kk = 0; kk < 2; ++kk)
#pragma unroll
                for (int mi = 0; mi < 4; ++mi)
                    acc[mi][2 + ni] = __builtin_amdgcn_mfma_f32_16x16x32_bf16(sq[mi][kk], aq1[ni][kk], acc[mi][2 + ni], 0, 0, 0);
        __builtin_amdgcn_s_setprio(0);
        BAR();
        // ---- ph3: read S q1; stage A both halves(t+2); MFMA q(1,0)
#pragma unroll
        for (int mi = 0; mi < 4; ++mi)
#pragma unroll
            for (int kk = 0; kk < 2; ++kk) sq[mi][kk] = readS(buf, 4 + mi, kk);
        stage_A(ktn, 0, buf);
        stage_A(ktn, 1, buf);
        BAR(); LGKM0();
        __builtin_amdgcn_s_setprio(1);
#pragma unroll
        for (int ni = 0; ni < 2; ++ni)
#pragma unroll
            for (int kk = 0; kk < 2; ++kk)
#pragma unroll
                for (int mi = 0; mi < 4; ++mi)
                    acc[4 + mi][ni] = __builtin_amdgcn_mfma_f32_16x16x32_bf16(sq[mi][kk], aq0[ni][kk], acc[4 + mi][ni], 0, 0, 0);
        __builtin_amdgcn_s_setprio(0);
        BAR();
        // ---- ph4: stage S-half1(t+2); MFMA q(1,1)
        stage_S(ktn, 1, buf);
        VM10();
        BAR();
        __builtin_amdgcn_s_setprio(1);
#pragma unroll
        for (int ni = 0; ni < 2; ++ni)
#pragma unroll
            for (int kk = 0; kk < 2; ++kk)
#pragma unroll
                for (int mi = 0; mi < 4; ++mi)
                    acc[4 + mi][2 + ni] = __builtin_amdgcn_mfma_f32_16x16x32_bf16(sq[mi][kk], aq1[ni][kk], acc[4 + mi][2 + ni], 0, 0, 0);
        __builtin_amdgcn_s_setprio(0);
        BAR();
    }

    // tail: tiles NT-2, NT-1 (no staging; single drain)
    VM0();
    BAR();
#pragma unroll 1
    for (int t = NT - 2; t < NT; ++t) {
        const int buf = t & 1;
#pragma unroll
        for (int kk = 0; kk < 2; ++kk) {
            bf16x8 sfr[8], afr[4];
#pragma unroll
            for (int m = 0; m < 8; ++m) sfr[m] = readS(buf, m, kk);
#pragma unroll
            for (int n = 0; n < 4; ++n) afr[n] = readA(buf, n, kk);
#pragma unroll
            for (int n = 0; n < 4; ++n)
#pragma unroll
                for (int m = 0; m < 8; ++m)
                    acc[m][n] = __builtin_amdgcn_mfma_f32_16x16x32_bf16(sfr[m], afr[n], acc[m][n], 0, 0, 0);
        }
    }

    // ---- split-K pair reduction via semaphore (G16: agent-scope) ----
    const int j0w = by * 256 + wm * 128;
    const int k0w = bx * 256 + wn * 64;

    if (tid == 0)
        role_sh = __hip_atomic_fetch_add(&flag_arrive[tile], 1u,
                                         __ATOMIC_RELAXED, __HIP_MEMORY_SCOPE_AGENT);
    __syncthreads();

    if (role_sh == 0) {
        // first arriver: publish partials
#pragma unroll
        for (int m = 0; m < 8; ++m)
#pragma unroll
            for (int r = 0; r < 4; ++r) {
                const int j = j0w + m * 16 + lq * 4 + r;
#pragma unroll
                for (int n = 0; n < 4; ++n)
                    Cpart[(size_t)j * K_SZ + k0w + n * 16 + l15] = acc[m][n][r];
            }
        __threadfence();
        __syncthreads();
        if (tid == 0)
            __hip_atomic_store(&flag_ready[tile], 1u,
                               __ATOMIC_RELEASE, __HIP_MEMORY_SCOPE_AGENT);
        return;
    }

    // second arriver: wait, reduce, sign/hash/defer
    if (tid == 0) {
        while (__hip_atomic_load(&flag_ready[tile],
                                 __ATOMIC_ACQUIRE, __HIP_MEMORY_SCOPE_AGENT) == 0u)
            __builtin_amdgcn_s_sleep(2);
    }
    __syncthreads();
    __threadfence();

#pragma unroll
    for (int m = 0; m < 8; ++m) {
#pragma unroll
        for (int r = 0; r < 4; ++r) {
            const int j = j0w + m * 16 + lq * 4 + r;
            const float bj = bvec[j];
            unsigned int sum = 0;
#pragma unroll
            for (int n = 0; n < 4; ++n) {
                const int k = k0w + n * 16 + l15;
                const float x = (Cpart[(size_t)j * K_SZ + k] + acc[m][n][r]) + bj;
                if (__builtin_fabsf(x) <= MARGIN) {
                    unsigned int slot = atomicAdd(defer_cnt, 1u);
                    if (slot < defer_cap)
                        defer_list[slot] = ((unsigned int)j << 12) | (unsigned int)k;
                } else if (x > 0.0f) {
                    sum += (unsigned int)hash_coeffs[k];
                }
            }
            sum += (unsigned int)__shfl_xor((int)sum, 1);
            sum += (unsigned int)__shfl_xor((int)sum, 2);
            sum += (unsigned int)__shfl_xor((int)sum, 4);
            sum += (unsigned int)__shfl_xor((int)sum, 8);
            if (l15 == 0) atomicAdd(&hash_acc[j], sum);
        }
    }
}

// ===========================================================================
// MID PATH (R3, proven): in ws-layout of its own.
// ===========================================================================
__global__ __launch_bounds__(256)
void opiq_split(const float* __restrict__ states,
                const float* __restrict__ actions,
                const float* __restrict__ A,
                ushort_t* __restrict__ Shi, ushort_t* __restrict__ Slo,
                ushort_t* __restrict__ Ahi, ushort_t* __restrict__ Alo)
{
    const long long NS = (long long)B_SZ * KD;
    const long long NA = (long long)K_SZ * KD;
    const long long stride = (long long)gridDim.x * 256;
    for (long long i = (long long)blockIdx.x * 256 + threadIdx.x;
         i < NS + NA; i += stride) {
        float v; int r, d; ushort_t *hi, *lo;
        if (i < NS) {
            r = (int)(i >> 11); d = (int)(i & 2047);
            v = (d == D_SZ) ? actions[r] : states[(size_t)r * D_SZ + d];
            hi = Shi; lo = Slo;
        } else {
            long long ii = i - NS;
            r = (int)(ii >> 11); d = (int)(ii & 2047);
            v = A[(size_t)r * KD + d];
            hi = Ahi; lo = Alo;
        }
        const int key = (r >> 1) & 3;
        const int dd = (d & ~24) | ((((d >> 3) & 3) ^ key) << 3);
        const ushort_t h = f2bf_rn(v);
        const ushort_t l2 = f2bf_rn(v - bf2f(h));
        hi[(size_t)r * KD + dd] = h;
        lo[(size_t)r * KD + dd] = l2;
    }
}

__global__ __launch_bounds__(256)
void opiq_gemm_mfma(const ushort_t* __restrict__ Shi, const ushort_t* __restrict__ Slo,
                    const ushort_t* __restrict__ Ahi, const ushort_t* __restrict__ Alo,
                    const float* __restrict__ bvec,
                    const int* __restrict__ hash_coeffs,
                    unsigned int* __restrict__ hash_acc,
                    unsigned int* __restrict__ defer_cnt,
                    unsigned int* __restrict__ defer_list,
                    unsigned int defer_cap)
{
    __shared__ __align__(16) ushort_t lds[2][4][TJ * BK];
    const int tid  = threadIdx.x;
    const int lane = tid & 63;
    const int w    = tid >> 6;
    const int wj   = w >> 1;
    const int wk   = w & 1;
    const int bid = blockIdx.x;
    const int swz = (bid & 7) * 64 + (bid >> 3);
    const int bx = swz & 31;
    const int by = swz >> 5;
    const int j0 = by * TJ;
    const int k0 = bx * TK;
    const ushort_t* gp[4] = { Shi + (size_t)j0 * KD, Slo + (size_t)j0 * KD,
                              Ahi + (size_t)k0 * KD, Alo + (size_t)k0 * KD };
    const int c1 = w * 64 + lane;
    const int c2 = c1 + 256;
    f32x4 acc[4][4];
#pragma unroll
    for (int m = 0; m < 4; ++m)
#pragma unroll
        for (int n = 0; n < 4; ++n) acc[m][n] = (f32x4){0.f, 0.f, 0.f, 0.f};
    const int frow = lane & 15;
    const int key  = (frow >> 1) & 3;
    const int col  = ((lane >> 4) ^ key) * 8;
#define STAGE(buf, t)                                                          \
    do {                                                                       \
        const int d0_ = (t) * BK;                                              \
        _Pragma("unroll")                                                      \
        for (int p_ = 0; p_ < 4; ++p_) {                                       \
            { const int row_ = c1 >> 2, cc_ = c1 & 3;                          \
              gl_lds16(gp[p_] + (size_t)row_ * KD + d0_ + cc_ * 8,             \
                       &lds[buf][p_][c1 * 8]); }                               \
            { const int row_ = c2 >> 2, cc_ = c2 & 3;                          \
              gl_lds16(gp[p_] + (size_t)row_ * KD + d0_ + cc_ * 8,             \
                       &lds[buf][p_][c2 * 8]); }                               \
        }                                                                      \
    } while (0)
    STAGE(0, 0);
    __syncthreads();
    for (int t = 0; t < KD / BK; ++t) {
        const int cur = t & 1;
        if (t < KD / BK - 1) STAGE(cur ^ 1, t + 1);
        bf16x8 sh[4], sl[4];
#pragma unroll
        for (int m = 0; m < 4; ++m) {
            sh[m] = *reinterpret_cast<const bf16x8*>(&lds[cur][0][(wj * 64 + m * 16 + frow) * BK + col]);
            sl[m] = *reinterpret_cast<const bf16x8*>(&lds[cur][1][(wj * 64 + m * 16 + frow) * BK + col]);
        }
#pragma unroll
        for (int n = 0; n < 4; ++n) {
            const bf16x8 ah = *reinterpret_cast<const bf16x8*>(&lds[cur][2][(wk * 64 + n * 16 + frow) * BK + col]);
            const bf16x8 al = *reinterpret_cast<const bf16x8*>(&lds[cur][3][(wk * 64 + n * 16 + frow) * BK + col]);
#pragma unroll
            for (int m = 0; m < 4; ++m) {
                acc[m][n] = __builtin_amdgcn_mfma_f32_16x16x32_bf16(sh[m], ah, acc[m][n], 0, 0, 0);
                acc[m][n] = __builtin_amdgcn_mfma_f32_16x16x32_bf16(sh[m], al, acc[m][n], 0, 0, 0);
                acc[m][n] = __builtin_amdgcn_mfma_f32_16x16x32_bf16(sl[m], ah, acc[m][n], 0, 0, 0);
            }
        }
        __syncthreads();
    }
#undef STAGE
#pragma unroll
    for (int m = 0; m < 4; ++m) {
#pragma unroll
        for (int r = 0; r < 4; ++r) {
            const int j = j0 + wj * 64 + m * 16 + (lane >> 4) * 4 + r;
            const float bj = bvec[j];
            unsigned int sum = 0;
#pragma unroll
            for (int n = 0; n < 4; ++n) {
                const int k = k0 + wk * 64 + n * 16 + (lane & 15);
                const float x = acc[m][n][r] + bj;
                if (__builtin_fabsf(x) <= MARGIN) {
                    unsigned int slot = atomicAdd(defer_cnt, 1u);
                    if (slot < defer_cap)
                        defer_list[slot] = ((unsigned int)j << 12) | (unsigned int)k;
                } else if (x > 0.0f) {
                    sum += (unsigned int)hash_coeffs[k];
                }
            }
            sum += (unsigned int)__shfl_xor((int)sum, 1);
            sum += (unsigned int)__shfl_xor((int)sum, 2);
            sum += (unsigned int)__shfl_xor((int)sum, 4);
            sum += (unsigned int)__shfl_xor((int)sum, 8);
            if ((lane & 15) == 0) atomicAdd(&hash_acc[j], sum);
        }
    }
}

// DEEP FALLBACK: exact fp64
__global__ __launch_bounds__(256)
void opiq_gemm_f64(const float* __restrict__ states,
                   const float* __restrict__ actions,
                   const float* __restrict__ A,
                   const float* __restrict__ bvec,
                   const int* __restrict__ hash_coeffs,
                   unsigned int* __restrict__ hash_acc)
{
    __shared__ float Slds[64][33];
    __shared__ float Alds[64][33];
    const int tid = threadIdx.x;
    const int tx = tid & 15;
    const int ty = tid >> 4;
    const int j0 = blockIdx.y * 64;
    const int k0 = blockIdx.x * 64;
    double acc[4][4];
#pragma unroll
    for (int i = 0; i < 4; ++i)
#pragma unroll
        for (int jj = 0; jj < 4; ++jj) acc[i][jj] = 0.0;
    for (int d0 = 0; d0 < KD; d0 += 32) {
#pragma unroll
        for (int t = 0; t < 8; ++t) {
            int flat = t * 256 + tid;
            int r = flat >> 5, c = flat & 31;
            int d = d0 + c;
            Slds[r][c] = (d == D_SZ) ? actions[j0 + r] : states[(size_t)(j0 + r) * D_SZ + d];
            Alds[r][c] = A[(size_t)(k0 + r) * KD + d];
        }
        __syncthreads();
#pragma unroll
        for (int dd = 0; dd < 32; ++dd) {
            double s[4], a[4];
#pragma unroll
            for (int i = 0; i < 4; ++i) s[i] = (double)Slds[ty * 4 + i][dd];
#pragma unroll
            for (int jj = 0; jj < 4; ++jj) a[jj] = (double)Alds[tx * 4 + jj][dd];
#pragma unroll
            for (int i = 0; i < 4; ++i)
#pragma unroll
                for (int jj = 0; jj < 4; ++jj)
                    acc[i][jj] = fma(s[i], a[jj], acc[i][jj]);
        }
        __syncthreads();
    }
#pragma unroll
    for (int i = 0; i < 4; ++i) {
        const int j = j0 + ty * 4 + i;
        const double bj = (double)bvec[j];
        unsigned int sum = 0;
#pragma unroll
        for (int jj = 0; jj < 4; ++jj) {
            const int k = k0 + tx * 4 + jj;
            if (acc[i][jj] + bj > 0.0) sum += (unsigned int)hash_coeffs[k];
        }
        sum += (unsigned int)__shfl_xor((int)sum, 1);
        sum += (unsigned int)__shfl_xor((int)sum, 2);
        sum += (unsigned int)__shfl_xor((int)sum, 4);
        sum += (unsigned int)__shfl_xor((int)sum, 8);
        if (tx == 0) atomicAdd(&hash_acc[j], sum);
    }
}

__global__ __launch_bounds__(256)
void opiq_fixup(const float* __restrict__ states,
                const float* __restrict__ actions,
                const float* __restrict__ A,
                const float* __restrict__ bvec,
                const int* __restrict__ hash_coeffs,
                unsigned int* __restrict__ hash_acc,
                const unsigned int* __restrict__ defer_cnt,
                const unsigned int* __restrict__ defer_list,
                unsigned int defer_cap)
{
    const int gtid = blockIdx.x * 256 + threadIdx.x;
    const int wave = gtid >> 6;
    const int lane = gtid & 63;
    const int n_waves = gridDim.x * 4;
    unsigned int n = *defer_cnt;
    if (n > defer_cap) n = defer_cap;
    for (unsigned int e = wave; e < n; e += n_waves) {
        const unsigned int ent = defer_list[e];
        const int j = (int)(ent >> 12);
        const int k = (int)(ent & 4095);
        double part = 0.0;
        const int dbase = lane * 32;
#pragma unroll 8
        for (int t = 0; t < 32; ++t) {
            const int d = dbase + t;
            const float sv = (d == D_SZ) ? actions[j] : states[(size_t)j * D_SZ + d];
            part = fma((double)sv, (double)A[(size_t)k * KD + d], part);
        }
#pragma unroll
        for (int m = 1; m < 64; m <<= 1)
            part += __shfl_xor(part, m);
        const double x = part + (double)bvec[j];
        if (lane == 0 && x > 0.0)
            atomicAdd(&hash_acc[j], (unsigned int)hash_coeffs[k]);
    }
}

__global__ void opiq_final(const unsigned int* __restrict__ hash_acc,
                           const int* __restrict__ count_table,
                           float* __restrict__ out)
{
    int j = blockIdx.x * 256 + threadIdx.x;
    if (j < B_SZ) {
        unsigned int idx = hash_acc[j] & TABLE_MASK;
        float c = (float)count_table[idx];
        float t = c + 1.0f;
        out[j] = 1.0f / (t * t);
    }
}

extern "C" void kernel_launch(void* const* d_in, const int* in_sizes, int n_in,
                              void* d_out, int out_size, void* d_ws, size_t ws_size,
                              hipStream_t stream) {
    const float* states      = (const float*)d_in[0];
    const float* actions     = (const float*)d_in[1];
    const float* A           = (const float*)d_in[2];
    const float* bvec        = (const float*)d_in[3];
    const int*   count_table = (const int*)d_in[4];
    const int*   hash_coeffs = (const int*)d_in[5];
    float* out = (float*)d_out;

    unsigned int* hash_acc  = (unsigned int*)d_ws;
    unsigned int* defer_cnt = hash_acc + B_SZ;

    // 8PH layout (identical REQ to R4's proven-fitting 84,951,040 B):
    // [0,8K) hash_acc | 8K defer_cnt | 8448 flagA(128) | 8960 flagB(128)
    // [16K, 16K+1M) defer_list | [+1M, +34.5M) Cpart | planes (50.3MB)
    const size_t DEFER_OFF = 16384;
    const size_t DEFER_CAP = 262144;
    const size_t C_OFF     = DEFER_OFF + DEFER_CAP * 4;     // 1,064,960
    const size_t C_BYTES   = (size_t)B_SZ * K_SZ * 4;       // 33,554,432
    const size_t PLANES_OFF = C_OFF + C_BYTES;
    const size_t S_ELEMS = (size_t)B_SZ * KD;
    const size_t A_ELEMS = (size_t)K_SZ * KD;
    const size_t REQ_8PH = PLANES_OFF + 2 * (S_ELEMS + A_ELEMS) * 2;

    const size_t DEFER_CAP_M  = 1u << 20;
    const size_t PLANES_OFF_M = DEFER_OFF + DEFER_CAP_M * 4;
    const size_t REQ_MID = PLANES_OFF_M + 2 * (S_ELEMS + A_ELEMS) * 2;

    if (ws_size >= REQ_8PH) {
        unsigned int* flagA = (unsigned int*)((char*)d_ws + 8448);
        unsigned int* flagB = (unsigned int*)((char*)d_ws + 8960);
        unsigned int* defer_list = (unsigned int*)((char*)d_ws + DEFER_OFF);
        float*    Cpart = (float*)((char*)d_ws + C_OFF);
        ushort_t* Shi_p = (ushort_t*)((char*)d_ws + PLANES_OFF);
        ushort_t* Slo_p = Shi_p + S_ELEMS;
        ushort_t* Ahi_p = Slo_p + S_ELEMS;
        ushort_t* Alo_p = Ahi_p + A_ELEMS;

        hipMemsetAsync(d_ws, 0, DEFER_OFF, stream);
        opiq_split8<<<6144, 256, 0, stream>>>(states, actions, A,
                                              Shi_p, Slo_p, Ahi_p, Alo_p);
        opiq_gemm_8ph<<<256, 512, 0, stream>>>(Shi_p, Slo_p, Ahi_p, Alo_p,
                                               bvec, hash_coeffs, Cpart,
                                               flagA, flagB, hash_acc,
                                               defer_cnt, defer_list,
                                               (unsigned int)DEFER_CAP);
        opiq_fixup<<<128, 256, 0, stream>>>(states, actions, A, bvec, hash_coeffs,
                                            hash_acc, defer_cnt, defer_list,
                                            (unsigned int)DEFER_CAP);
    } else if (ws_size >= REQ_MID) {
        unsigned int* defer_list = (unsigned int*)((char*)d_ws + DEFER_OFF);
        ushort_t* Shi = (ushort_t*)((char*)d_ws + PLANES_OFF_M);
        ushort_t* Slo = Shi + S_ELEMS;
        ushort_t* Ahi = Slo + S_ELEMS;
        ushort_t* Alo = Ahi + A_ELEMS;

        hipMemsetAsync(d_ws, 0, DEFER_OFF, stream);
        opiq_split<<<4096, 256, 0, stream>>>(states, actions, A, Shi, Slo, Ahi, Alo);
        opiq_gemm_mfma<<<512, 256, 0, stream>>>(Shi, Slo, Ahi, Alo, bvec,
                                                hash_coeffs, hash_acc,
                                                defer_cnt, defer_list,
                                                (unsigned int)DEFER_CAP_M);
        opiq_fixup<<<128, 256, 0, stream>>>(states, actions, A, bvec, hash_coeffs,
                                            hash_acc, defer_cnt, defer_list,
                                            (unsigned int)DEFER_CAP_M);
    } else {
        hipMemsetAsync(d_ws, 0, B_SZ * sizeof(unsigned int), stream);
        dim3 grid(K_SZ / 64, B_SZ / 64);
        opiq_gemm_f64<<<grid, 256, 0, stream>>>(states, actions, A, bvec,
                                                hash_coeffs, hash_acc);
    }
    opiq_final<<<(B_SZ + 255) / 256, 256, 0, stream>>>(hash_acc, count_table, out);
}

// Round 7
// 202.956 us; speedup vs baseline: 1.5801x; 1.5801x over previous
//
#include <hip/hip_runtime.h>
#include <stdint.h>

// Problem constants (fixed by setup_inputs)
#define B_SZ 2048          // batch
#define D_SZ 2047          // state dim
#define KD   2048          // D+1 == hash_size
#define K_SZ 4096          // input_length (rows of A)
#define TABLE_MASK ((1u << 22) - 1)
#define MARGIN 0.03f       // 3-pass bf16-split worst-case error ~1.3e-2; 2.3x headroom

#define BM 128             // batch tile
#define BN 256             // k tile
#define BK 32              // inner-dim step (== MFMA K)
#define NTILES (KD / BK)   // 64

typedef __attribute__((ext_vector_type(8))) short bf16x8;
typedef __attribute__((ext_vector_type(4))) float f32x4;
typedef unsigned short ushort_t;

__device__ __forceinline__ unsigned short f2bf_rn(float x) {
    unsigned int u = __builtin_bit_cast(unsigned int, x);
    unsigned int lsb = (u >> 16) & 1u;
    u += 0x7fffu + lsb;                 // round-to-nearest-even
    return (unsigned short)(u >> 16);
}
__device__ __forceinline__ float bf2f(unsigned short h) {
    unsigned int u = ((unsigned int)h) << 16;
    return __builtin_bit_cast(float, u);
}
__device__ __forceinline__ void gl_lds16(const void* g, void* l) {
    __builtin_amdgcn_global_load_lds(
        (const __attribute__((address_space(1))) unsigned int*)g,
        (__attribute__((address_space(3))) unsigned int*)l, 16, 0, 0);
}

#define BAR()  asm volatile("s_barrier" ::: "memory")
#define VM6()  asm volatile("s_waitcnt vmcnt(6)" ::: "memory")
#define VM0()  asm volatile("s_waitcnt vmcnt(0)" ::: "memory")

// ---------------------------------------------------------------------------
// Pass 0 (R3-proven): split f32 -> (bf16 hi, bf16 lo) planes, 16B-chunk XOR
// swizzle pre-baked into the global layout (key = (row>>1)&3 on d bits 3..4).
// ---------------------------------------------------------------------------
__global__ __launch_bounds__(256)
void opiq_split(const float* __restrict__ states,
                const float* __restrict__ actions,
                const float* __restrict__ A,
                ushort_t* __restrict__ Shi, ushort_t* __restrict__ Slo,
                ushort_t* __restrict__ Ahi, ushort_t* __restrict__ Alo)
{
    const long long NS = (long long)B_SZ * KD;
    const long long NA = (long long)K_SZ * KD;
    const long long stride = (long long)gridDim.x * 256;
    for (long long i = (long long)blockIdx.x * 256 + threadIdx.x;
         i < NS + NA; i += stride) {
        float v; int r, d; ushort_t *hi, *lo;
        if (i < NS) {
            r = (int)(i >> 11); d = (int)(i & 2047);
            v = (d == D_SZ) ? actions[r] : states[(size_t)r * D_SZ + d];
            hi = Shi; lo = Slo;
        } else {
            long long ii = i - NS;
            r = (int)(ii >> 11); d = (int)(ii & 2047);
            v = A[(size_t)r * KD + d];
            hi = Ahi; lo = Alo;
        }
        const int key = (r >> 1) & 3;
        const int dd = (d & ~24) | ((((d >> 3) & 3) ^ key) << 3);
        const ushort_t h = f2bf_rn(v);
        const ushort_t l2 = f2bf_rn(v - bf2f(h));
        hi[(size_t)r * KD + dd] = h;
        lo[(size_t)r * KD + dd] = l2;
    }
}

// ---------------------------------------------------------------------------
// Main GEMM: 128x256 tile, 512 threads (8 waves, 2M x 4N), BK=32.
// 3-buffer LDS pipeline (R4-proven loop): STAGE(t+2) issued before compute(t),
// one s_barrier per K-tile, counted vmcnt(6) (6 loads/thread/tile).
// In-register epilogue: sign -> weighted hash; borderline -> fp64 fixup list.
// ---------------------------------------------------------------------------
__global__ __launch_bounds__(512, 1)
void opiq_gemm_p3(const ushort_t* __restrict__ Shi, const ushort_t* __restrict__ Slo,
                  const ushort_t* __restrict__ Ahi, const ushort_t* __restrict__ Alo,
                  const float* __restrict__ bvec,
                  const int* __restrict__ hash_coeffs,
                  unsigned int* __restrict__ hash_acc,
                  unsigned int* __restrict__ defer_cnt,
                  unsigned int* __restrict__ defer_list,
                  unsigned int defer_cap)
{
    // per buffer (ushorts): Shi[128][32] @0, Slo @4096, Ahi[256][32] @8192, Alo @16384
    __shared__ __align__(16) ushort_t lds[3][24576];   // 144 KB

    const int tid  = threadIdx.x;
    const int lane = tid & 63;
    const int wid  = tid >> 6;          // 8 waves: 2(M) x 4(N)
    const int wj   = wid >> 2;
    const int wk   = wid & 3;
    const int l15  = lane & 15;
    const int lq   = lane >> 4;

    // XCD swizzle (256 % 8 == 0, bijective). bx groups share A panels in L2.
    const int bid = blockIdx.x;
    const int swz = (bid & 7) * 32 + (bid >> 3);
    const int bx  = swz >> 4;           // [0,16) k-tile
    const int by  = swz & 15;           // [0,16) j-tile
    const int j0  = by * BM;
    const int k0  = bx * BN;

    // 6 staging source pointers (16B chunk per gl_lds16), R3-proven mapping:
    // chunk c of a plane: row = c>>2, 16B-slot = c&3  (linear LDS dest = c*16B)
    const int srow = tid >> 2, sslot = (tid & 3) * 8;
    const ushort_t* pSh  = Shi + (size_t)(j0 + srow) * KD + sslot;
    const ushort_t* pSl  = Slo + (size_t)(j0 + srow) * KD + sslot;
    const ushort_t* pAh0 = Ahi + (size_t)(k0 + srow) * KD + sslot;
    const ushort_t* pAh1 = Ahi + (size_t)(k0 + 128 + srow) * KD + sslot;
    const ushort_t* pAl0 = Alo + (size_t)(k0 + srow) * KD + sslot;
    const ushort_t* pAl1 = Alo + (size_t)(k0 + 128 + srow) * KD + sslot;
    const int dS  = tid * 8;
    const int dA0 = 8192 + tid * 8;
    const int dA1 = 8192 + 4096 + tid * 8;

    auto STAGE = [&](int t, int s) {
        const int o = t * BK;           // ushort offset along d
        gl_lds16(pSh  + o, &lds[s][dS]);
        gl_lds16(pSl  + o, &lds[s][4096 + dS]);
        gl_lds16(pAh0 + o, &lds[s][dA0]);
        gl_lds16(pAh1 + o, &lds[s][dA1]);
        gl_lds16(pAl0 + o, &lds[s][8192 + dA0]);
        gl_lds16(pAl1 + o, &lds[s][8192 + dA1]);
    };

    f32x4 acc[4][4];
#pragma unroll
    for (int m = 0; m < 4; ++m)
#pragma unroll
        for (int n = 0; n < 4; ++n) acc[m][n] = (f32x4){0.f, 0.f, 0.f, 0.f};

    const int frow = lane & 15;
    const int key  = (frow >> 1) & 3;
    const int col  = ((lane >> 4) ^ key) * 8;   // swizzled 16B-chunk (ushorts)

    auto do_tile = [&](const ushort_t* lb) {
        bf16x8 sh[4], sl[4];
#pragma unroll
        for (int m = 0; m < 4; ++m) {
            const int ro = (wj * 64 + m * 16 + frow) * BK + col;
            sh[m] = *reinterpret_cast<const bf16x8*>(&lb[ro]);
            sl[m] = *reinterpret_cast<const bf16x8*>(&lb[4096 + ro]);
        }
#pragma unroll
        for (int n = 0; n < 4; ++n) {
            const int ro = (wk * 64 + n * 16 + frow) * BK + col;
            const bf16x8 ah = *reinterpret_cast<const bf16x8*>(&lb[8192 + ro]);
            const bf16x8 al = *reinterpret_cast<const bf16x8*>(&lb[16384 + ro]);
#pragma unroll
            for (int m = 0; m < 4; ++m) {
                acc[m][n] = __builtin_amdgcn_mfma_f32_16x16x32_bf16(sh[m], ah, acc[m][n], 0, 0, 0);
                acc[m][n] = __builtin_amdgcn_mfma_f32_16x16x32_bf16(sh[m], al, acc[m][n], 0, 0, 0);
                acc[m][n] = __builtin_amdgcn_mfma_f32_16x16x32_bf16(sl[m], ah, acc[m][n], 0, 0, 0);
            }
        }
    };

    // prologue: tiles 0,1 in flight; require tile0 landed (6 newest may fly)
    STAGE(0, 0);
    STAGE(1, 1);
    VM6();
    BAR();

    int cur = 0, stg = 2;
#pragma unroll 1
    for (int t = 0; t < NTILES; ++t) {
        if (t < NTILES - 2) STAGE(t + 2, stg);
        do_tile(lds[cur]);
        if (t < NTILES - 2)      VM6();   // tile t+1's 6 loads landed
        else if (t == NTILES - 2) VM0();  // drain for the last tile
        if (t < NTILES - 1) BAR();
        cur = (cur == 2) ? 0 : cur + 1;
        stg = (stg == 2) ? 0 : stg + 1;
    }

    // ---- epilogue: C/D layout col=lane&15, row=(lane>>4)*4+reg
#pragma unroll
    for (int m = 0; m < 4; ++m) {
#pragma unroll
        for (int r = 0; r < 4; ++r) {
            const int j = j0 + wj * 64 + m * 16 + lq * 4 + r;
            const float bj = bvec[j];
            unsigned int sum = 0;
#pragma unroll
            for (int n = 0; n < 4; ++n) {
                const int k = k0 + wk * 64 + n * 16 + l15;
                const float x = acc[m][n][r] + bj;
                if (__builtin_fabsf(x) <= MARGIN) {
                    unsigned int slot = atomicAdd(defer_cnt, 1u);
                    if (slot < defer_cap)
                        defer_list[slot] = ((unsigned int)j << 12) | (unsigned int)k;
                } else if (x > 0.0f) {
                    sum += (unsigned int)hash_coeffs[k];
                }
            }
            sum += (unsigned int)__shfl_xor((int)sum, 1);
            sum += (unsigned int)__shfl_xor((int)sum, 2);
            sum += (unsigned int)__shfl_xor((int)sum, 4);
            sum += (unsigned int)__shfl_xor((int)sum, 8);
            if (l15 == 0) atomicAdd(&hash_acc[j], sum);
        }
    }
}

// ---------------------------------------------------------------------------
// DEEP FALLBACK: exact fp64 (R0-proven), needs only hash_acc.
// ---------------------------------------------------------------------------
__global__ __launch_bounds__(256)
void opiq_gemm_f64(const float* __restrict__ states,
                   const float* __restrict__ actions,
                   const float* __restrict__ A,
                   const float* __restrict__ bvec,
                   const int* __restrict__ hash_coeffs,
                   unsigned int* __restrict__ hash_acc)
{
    __shared__ float Slds[64][33];
    __shared__ float Alds[64][33];
    const int tid = threadIdx.x;
    const int tx = tid & 15;
    const int ty = tid >> 4;
    const int j0 = blockIdx.y * 64;
    const int k0 = blockIdx.x * 64;
    double acc[4][4];
#pragma unroll
    for (int i = 0; i < 4; ++i)
#pragma unroll
        for (int jj = 0; jj < 4; ++jj) acc[i][jj] = 0.0;
    for (int d0 = 0; d0 < KD; d0 += 32) {
#pragma unroll
        for (int t = 0; t < 8; ++t) {
            int flat = t * 256 + tid;
            int r = flat >> 5, c = flat & 31;
            int d = d0 + c;
            Slds[r][c] = (d == D_SZ) ? actions[j0 + r] : states[(size_t)(j0 + r) * D_SZ + d];
            Alds[r][c] = A[(size_t)(k0 + r) * KD + d];
        }
        __syncthreads();
#pragma unroll
        for (int dd = 0; dd < 32; ++dd) {
            double s[4], a[4];
#pragma unroll
            for (int i = 0; i < 4; ++i) s[i] = (double)Slds[ty * 4 + i][dd];
#pragma unroll
            for (int jj = 0; jj < 4; ++jj) a[jj] = (double)Alds[tx * 4 + jj][dd];
#pragma unroll
            for (int i = 0; i < 4; ++i)
#pragma unroll
                for (int jj = 0; jj < 4; ++jj)
                    acc[i][jj] = fma(s[i], a[jj], acc[i][jj]);
        }
        __syncthreads();
    }
#pragma unroll
    for (int i = 0; i < 4; ++i) {
        const int j = j0 + ty * 4 + i;
        const double bj = (double)bvec[j];
        unsigned int sum = 0;
#pragma unroll
        for (int jj = 0; jj < 4; ++jj) {
            const int k = k0 + tx * 4 + jj;
            if (acc[i][jj] + bj > 0.0) sum += (unsigned int)hash_coeffs[k];
        }
        sum += (unsigned int)__shfl_xor((int)sum, 1);
        sum += (unsigned int)__shfl_xor((int)sum, 2);
        sum += (unsigned int)__shfl_xor((int)sum, 4);
        sum += (unsigned int)__shfl_xor((int)sum, 8);
        if (tx == 0) atomicAdd(&hash_acc[j], sum);
    }
}

// Exact fp64 recompute of deferred dots; one wave per deferred (j,k) pair.
__global__ __launch_bounds__(256)
void opiq_fixup(const float* __restrict__ states,
                const float* __restrict__ actions,
                const float* __restrict__ A,
                const float* __restrict__ bvec,
                const int* __restrict__ hash_coeffs,
                unsigned int* __restrict__ hash_acc,
                const unsigned int* __restrict__ defer_cnt,
                const unsigned int* __restrict__ defer_list,
                unsigned int defer_cap)
{
    const int gtid = blockIdx.x * 256 + threadIdx.x;
    const int wave = gtid >> 6;
    const int lane = gtid & 63;
    const int n_waves = gridDim.x * 4;
    unsigned int n = *defer_cnt;
    if (n > defer_cap) n = defer_cap;
    for (unsigned int e = wave; e < n; e += n_waves) {
        const unsigned int ent = defer_list[e];
        const int j = (int)(ent >> 12);
        const int k = (int)(ent & 4095);
        double part = 0.0;
        const int dbase = lane * 32;
#pragma unroll 8
        for (int t = 0; t < 32; ++t) {
            const int d = dbase + t;
            const float sv = (d == D_SZ) ? actions[j] : states[(size_t)j * D_SZ + d];
            part = fma((double)sv, (double)A[(size_t)k * KD + d], part);
        }
#pragma unroll
        for (int m = 1; m < 64; m <<= 1)
            part += __shfl_xor(part, m);
        const double x = part + (double)bvec[j];
        if (lane == 0 && x > 0.0)
            atomicAdd(&hash_acc[j], (unsigned int)hash_coeffs[k]);
    }
}

__global__ void opiq_final(const unsigned int* __restrict__ hash_acc,
                           const int* __restrict__ count_table,
                           float* __restrict__ out)
{
    int j = blockIdx.x * 256 + threadIdx.x;
    if (j < B_SZ) {
        unsigned int idx = hash_acc[j] & TABLE_MASK;
        float c = (float)count_table[idx];
        float t = c + 1.0f;
        out[j] = 1.0f / (t * t);
    }
}

extern "C" void kernel_launch(void* const* d_in, const int* in_sizes, int n_in,
                              void* d_out, int out_size, void* d_ws, size_t ws_size,
                              hipStream_t stream) {
    const float* states      = (const float*)d_in[0];
    const float* actions     = (const float*)d_in[1];
    const float* A           = (const float*)d_in[2];
    const float* bvec        = (const float*)d_in[3];
    const int*   count_table = (const int*)d_in[4];
    const int*   hash_coeffs = (const int*)d_in[5];
    float* out = (float*)d_out;

    unsigned int* hash_acc  = (unsigned int*)d_ws;
    unsigned int* defer_cnt = hash_acc + B_SZ;

    // ws: [0,8K) hash_acc | 8K defer_cnt | [16K,16K+4M) defer_list | planes (50.3MB)
    const size_t DEFER_OFF  = 16384;
    const size_t DEFER_CAP  = 1u << 20;
    const size_t PLANES_OFF = DEFER_OFF + DEFER_CAP * 4;
    const size_t S_ELEMS = (size_t)B_SZ * KD;
    const size_t A_ELEMS = (size_t)K_SZ * KD;
    const size_t REQ = PLANES_OFF + 2 * (S_ELEMS + A_ELEMS) * sizeof(ushort_t);

    if (ws_size >= REQ) {
        unsigned int* defer_list = (unsigned int*)((char*)d_ws + DEFER_OFF);
        ushort_t* Shi = (ushort_t*)((char*)d_ws + PLANES_OFF);
        ushort_t* Slo = Shi + S_ELEMS;
        ushort_t* Ahi = Slo + S_ELEMS;
        ushort_t* Alo = Ahi + A_ELEMS;

        hipMemsetAsync(d_ws, 0, DEFER_OFF, stream);
        opiq_split<<<4096, 256, 0, stream>>>(states, actions, A, Shi, Slo, Ahi, Alo);
        opiq_gemm_p3<<<256, 512, 0, stream>>>(Shi, Slo, Ahi, Alo, bvec,
                                              hash_coeffs, hash_acc,
                                              defer_cnt, defer_list,
                                              (unsigned int)DEFER_CAP);
        opiq_fixup<<<128, 256, 0, stream>>>(states, actions, A, bvec, hash_coeffs,
                                            hash_acc, defer_cnt, defer_list,
                                            (unsigned int)DEFER_CAP);
    } else {
        hipMemsetAsync(d_ws, 0, B_SZ * sizeof(unsigned int), stream);
        dim3 grid(K_SZ / 64, B_SZ / 64);
        opiq_gemm_f64<<<grid, 256, 0, stream>>>(states, actions, A, bvec,
                                                hash_coeffs, hash_acc);
    }
    opiq_final<<<(B_SZ + 255) / 256, 256, 0, stream>>>(hash_acc, count_table, out);
}